// Round 5
// baseline (4389.231 us; speedup 1.0000x reference)
//
#include <hip/hip_runtime.h>
#include <hip/hip_bf16.h>
#include <stdint.h>

// B=128, T=25, V=10000, E=512, NF=2048, H=512, MAP=512, IN0=1024
// Round 5: round-3 MFMA fast path + THE FIX: d_out is float32 (reference output
// dtype), not bf16. Logits and hidden written as f32.

typedef __hip_bfloat16 bf16;
typedef __attribute__((ext_vector_type(8))) short frag8;   // 8 bf16 = 4 VGPR
typedef __attribute__((ext_vector_type(4))) float f32x4;
typedef __attribute__((ext_vector_type(4))) unsigned int u32x4;

#define T_N 25

__device__ __forceinline__ float bf2f(bf16 x){ return __bfloat162float(x); }
__device__ __forceinline__ bf16 f2bf(float x){ return __float2bfloat16(x); }
__device__ __forceinline__ f32x4 mfma16(frag8 a, frag8 b, f32x4 c){
  return __builtin_amdgcn_mfma_f32_16x16x32_bf16(a, b, c, 0, 0, 0);
}
__device__ __forceinline__ void gld_lds16(const bf16* g, bf16* l){
  __builtin_amdgcn_global_load_lds((const __attribute__((address_space(1))) unsigned int*)g,
                                   (__attribute__((address_space(3))) unsigned int*)l, 16, 0, 0);
}
__device__ __forceinline__ float sigmoidf_(float x){ return 1.f/(1.f + __expf(-x)); }
__device__ __forceinline__ float tanhf_(float x){ return 2.f/(1.f + __expf(-2.f*x)) - 1.f; }

// ---------------- dtype detection ----------------
// flags[0]=1 -> float inputs are f32 (else bf16). flags[1]=1 -> tokens int64 (else int32).
__global__ __launch_bounds__(256) void detect_kernel(const unsigned short* __restrict__ embu,
    const int* __restrict__ tok32, int* __restrict__ flags){
  __shared__ int cF, cT;
  if (threadIdx.x == 0){ cF = 0; cT = 0; }
  __syncthreads();
  int bad = 0;
  for (int j = threadIdx.x; j < 512; j += 256){
    unsigned e = (embu[2*j] >> 7) & 0xFFu;
    if (e > 160u) bad++;                      // f32 low-halves trip this ~37%; bf16 N(0,1) never
  }
  if (bad) atomicAdd(&cF, bad);
  int nz = 0;
  for (int j = threadIdx.x; j < 128; j += 256)
    if (tok32[2*j + 1] != 0) nz++;            // int64 high words all zero
  if (nz) atomicAdd(&cT, nz);
  __syncthreads();
  if (threadIdx.x == 0){
    flags[0] = (cF > 8) ? 1 : 0;
    flags[1] = (cT < 4) ? 1 : 0;
  }
}

// ---------------- conversions ----------------
__global__ __launch_bounds__(256) void cvt_split(const void* __restrict__ src,
    bf16* __restrict__ hi, bf16* __restrict__ lo, int n, const int* __restrict__ flags){
  int i = (blockIdx.x*256 + threadIdx.x)*4;
  if (i >= n) return;
  bool isf = flags[0] != 0;
  #pragma unroll
  for (int j=0;j<4;j++){
    float x = isf ? ((const float*)src)[i+j] : bf2f(((const bf16*)src)[i+j]);
    bf16 h = f2bf(x);
    hi[i+j] = h;
    if (lo) lo[i+j] = f2bf(x - bf2f(h));
  }
}

struct CD { const void* src; float* dst; int n; };
struct CDs { CD d[8]; };
__global__ __launch_bounds__(256) void cvt_f32_batch(CDs all, const int* __restrict__ flags){
  CD d = all.d[blockIdx.y];
  int i = blockIdx.x*256 + threadIdx.x;
  if (i >= d.n) return;
  d.dst[i] = (flags[0] != 0) ? ((const float*)d.src)[i] : bf2f(((const bf16*)d.src)[i]);
}

// ---------------- init ----------------
__global__ __launch_bounds__(256) void init_zero(float* h0f, float* h1f,
    bf16* h0b, bf16* h0lb, bf16* h1b, bf16* h1lb){
  int i = blockIdx.x*256 + threadIdx.x;
  if (i < 65536){
    h0f[i] = 0.f; h1f[i] = 0.f;
    bf16 z = f2bf(0.f);
    h0b[i] = z; h0lb[i] = z; h1b[i] = z; h1lb[i] = z;
  }
}

// ---------------- transpose + split: dst[n*Kd+k] = split(src[(k0+k)*Ns+n]) ----------------
struct TD { const void* src; bf16* dh; bf16* dl; int k0, Kd, Nd, Ns, NsV; };
struct TDs { TD d[14]; };
__global__ __launch_bounds__(256) void transpose_many(TDs all, const int* __restrict__ flags){
  TD d = all.d[blockIdx.y];
  int tilesN = d.Nd >> 5, tilesK = d.Kd >> 5;
  if ((int)blockIdx.x >= tilesN*tilesK) return;
  bool isf = flags[0] != 0;
  int tn = blockIdx.x % tilesN, tk = blockIdx.x / tilesN;
  int nt0 = tn*32, kt0 = tk*32;
  __shared__ float tile[32][33];
  int tx = threadIdx.x & 31, ty = threadIdx.x >> 5;
  #pragma unroll
  for (int p=0;p<4;p++){
    int k = kt0 + ty + p*8, n = nt0 + tx;
    float v = 0.f;
    if (n < d.NsV){
      size_t idx = (size_t)(d.k0 + k)*d.Ns + n;
      v = isf ? ((const float*)d.src)[idx] : bf2f(((const bf16*)d.src)[idx]);
    }
    tile[ty + p*8][tx] = v;
  }
  __syncthreads();
  #pragma unroll
  for (int p=0;p<4;p++){
    int n = nt0 + ty + p*8, k = kt0 + tx;
    float v = tile[tx][ty + p*8];
    bf16 h = f2bf(v);
    d.dh[(size_t)n*d.Kd + k] = h;
    if (d.dl) d.dl[(size_t)n*d.Kd + k] = f2bf(v - bf2f(h));
  }
}

// ---------------- split GEMM: C = (Ah+Al)[M,K] @ (Bth+Btl)[N,K]^T + bias ----------------
// MODE 0: f32 out.  MODE 1: leaky_relu(0.01) + split bf16 out.
template<int MODE>
__global__ __launch_bounds__(256) void gemm_split(
    const bf16* __restrict__ Ah, const bf16* __restrict__ Al,
    const bf16* __restrict__ Bth, const bf16* __restrict__ Btl,
    const float* __restrict__ bias, float* __restrict__ C,
    bf16* __restrict__ Ch, bf16* __restrict__ Cl, int K, int N)
{
  __shared__ bf16 Ash[128*32], Asl[128*32], Bsh[128*32], Bsl[128*32];
  const int m0 = blockIdx.y*128, n0 = blockIdx.x*128;
  const int tid = threadIdx.x, lane = tid & 63, wave = tid >> 6;
  const int wr = wave >> 1, wc = wave & 1, cl = lane & 15, cq = lane >> 4;
  f32x4 acc[4][4];
  #pragma unroll
  for (int i=0;i<4;i++)
    #pragma unroll
    for (int j=0;j<4;j++) acc[i][j] = (f32x4){0.f,0.f,0.f,0.f};

  const int r0 = tid >> 2, kc0 = (tid & 3)*8;
  for (int kt = 0; kt < K; kt += 32){
    gld_lds16(Ah  + (size_t)(m0 + r0)*K      + kt + kc0, Ash + (wave*64)*8);
    gld_lds16(Ah  + (size_t)(m0 + 64 + r0)*K + kt + kc0, Ash + (256 + wave*64)*8);
    gld_lds16(Al  + (size_t)(m0 + r0)*K      + kt + kc0, Asl + (wave*64)*8);
    gld_lds16(Al  + (size_t)(m0 + 64 + r0)*K + kt + kc0, Asl + (256 + wave*64)*8);
    gld_lds16(Bth + (size_t)(n0 + r0)*K      + kt + kc0, Bsh + (wave*64)*8);
    gld_lds16(Bth + (size_t)(n0 + 64 + r0)*K + kt + kc0, Bsh + (256 + wave*64)*8);
    gld_lds16(Btl + (size_t)(n0 + r0)*K      + kt + kc0, Bsl + (wave*64)*8);
    gld_lds16(Btl + (size_t)(n0 + 64 + r0)*K + kt + kc0, Bsl + (256 + wave*64)*8);
    __syncthreads();
    frag8 ah[4], al[4], bh[4], bl[4];
    #pragma unroll
    for (int i=0;i<4;i++){
      ah[i] = *(const frag8*)(Ash + (64*wr + 16*i + cl)*32 + cq*8);
      al[i] = *(const frag8*)(Asl + (64*wr + 16*i + cl)*32 + cq*8);
      bh[i] = *(const frag8*)(Bsh + (64*wc + 16*i + cl)*32 + cq*8);
      bl[i] = *(const frag8*)(Bsl + (64*wc + 16*i + cl)*32 + cq*8);
    }
    #pragma unroll
    for (int i=0;i<4;i++)
      #pragma unroll
      for (int j=0;j<4;j++){
        acc[i][j] = mfma16(ah[i], bh[j], acc[i][j]);
        acc[i][j] = mfma16(ah[i], bl[j], acc[i][j]);
        acc[i][j] = mfma16(al[i], bh[j], acc[i][j]);
      }
    __syncthreads();
  }
  #pragma unroll
  for (int j=0;j<4;j++){
    int col = n0 + 64*wc + 16*j + cl;
    float bv = bias[col];
    #pragma unroll
    for (int i=0;i<4;i++){
      int rowb = m0 + 64*wr + 16*i + cq*4;
      #pragma unroll
      for (int v=0;v<4;v++){
        float val = acc[i][j][v] + bv;
        int row = rowb + v;
        if (MODE == 1){
          val = (val > 0.f) ? val : 0.01f*val;
          bf16 h = f2bf(val);
          Ch[(size_t)row*N + col] = h;
          Cl[(size_t)row*N + col] = f2bf(val - bf2f(h));
        } else {
          C[(size_t)row*N + col] = val;
        }
      }
    }
  }
}

// ---------------- logits GEMM: f32 out, row remap t*128+b -> b*25+t, col guard -------
__global__ __launch_bounds__(256) void gemm_logits(
    const bf16* __restrict__ A, const bf16* __restrict__ Bt,
    const float* __restrict__ bias, float* __restrict__ C, int K, int NV)
{
  __shared__ bf16 As[128*32];
  __shared__ bf16 Bs[128*32];
  const int m0 = blockIdx.y*128, n0 = blockIdx.x*128;
  const int tid = threadIdx.x, lane = tid & 63, wave = tid >> 6;
  const int wr = wave >> 1, wc = wave & 1, cl = lane & 15, cq = lane >> 4;
  f32x4 acc[4][4];
  #pragma unroll
  for (int i=0;i<4;i++)
    #pragma unroll
    for (int j=0;j<4;j++) acc[i][j] = (f32x4){0.f,0.f,0.f,0.f};
  const int r0 = tid >> 2, kc0 = (tid & 3)*8;
  for (int kt = 0; kt < K; kt += 32){
    gld_lds16(A  + (size_t)(m0 + r0)*K      + kt + kc0, As + (wave*64)*8);
    gld_lds16(A  + (size_t)(m0 + 64 + r0)*K + kt + kc0, As + (256 + wave*64)*8);
    gld_lds16(Bt + (size_t)(n0 + r0)*K      + kt + kc0, Bs + (wave*64)*8);
    gld_lds16(Bt + (size_t)(n0 + 64 + r0)*K + kt + kc0, Bs + (256 + wave*64)*8);
    __syncthreads();
    frag8 af[4], bfr[4];
    #pragma unroll
    for (int i=0;i<4;i++){
      af[i]  = *(const frag8*)(As + (64*wr + 16*i + cl)*32 + cq*8);
      bfr[i] = *(const frag8*)(Bs + (64*wc + 16*i + cl)*32 + cq*8);
    }
    #pragma unroll
    for (int i=0;i<4;i++)
      #pragma unroll
      for (int j=0;j<4;j++)
        acc[i][j] = mfma16(af[i], bfr[j], acc[i][j]);
    __syncthreads();
  }
  #pragma unroll
  for (int j=0;j<4;j++){
    int col = n0 + 64*wc + 16*j + cl;
    if (col >= NV) continue;
    float bv = bias[col];
    #pragma unroll
    for (int i=0;i<4;i++){
      int rowb = m0 + 64*wr + 16*i + cq*4;
      #pragma unroll
      for (int v=0;v<4;v++){
        int row = rowb + v;
        int b = row & 127, t = row >> 7;
        C[((size_t)b*T_N + t)*NV + col] = acc[i][j][v] + bv;   // f32 store
      }
    }
  }
}

// ---------------- X0A build: row r=t*128+b -> [emb[tok[b,t]] | p[b]] (hi, lo) ----------
__global__ __launch_bounds__(256) void build_x0a(const int* __restrict__ tok32,
    const bf16* __restrict__ embH, const bf16* __restrict__ embL,
    const bf16* __restrict__ pH, const bf16* __restrict__ pL,
    bf16* __restrict__ XH, bf16* __restrict__ XL, const int* __restrict__ flags)
{
  int r = blockIdx.x;             // 0..3199
  int t = r >> 7, b = r & 127;
  int idx = b*T_N + t;
  int tok = (flags[1] != 0) ? tok32[2*idx] : tok32[idx];
  int k = threadIdx.x * 4;
  uint2 hv, lv;
  if (k < 512){
    hv = *(const uint2*)(embH + (size_t)tok*512 + k);
    lv = *(const uint2*)(embL + (size_t)tok*512 + k);
  } else {
    hv = *(const uint2*)(pH + b*512 + (k - 512));
    lv = *(const uint2*)(pL + b*512 + (k - 512));
  }
  *(uint2*)(XH + (size_t)r*1024 + k) = hv;
  *(uint2*)(XL + (size_t)r*1024 + k) = lv;
}

// ---------------- GRU phase kernels (one launch per phase; M=128, K=512) ----------------
// Phase A: pre = h@[Wu|Wr] + Xall[:, 0:1024]; col<512 -> u=sig; col>=512 -> rh=sig*h
__global__ __launch_bounds__(256) void gru_phase_a(
    const bf16* __restrict__ hb, const bf16* __restrict__ hlb,
    const bf16* __restrict__ Wh, const bf16* __restrict__ Wl,
    const float* __restrict__ Xall, const float* __restrict__ hf,
    float* __restrict__ uf, bf16* __restrict__ rhb, bf16* __restrict__ rhlb, int t)
{
  __shared__ bf16 Ash[128*32], Asl[128*32], Bsh[128*32], Bsl[128*32];
  const int n0 = blockIdx.x*128;
  const int tid = threadIdx.x, lane = tid & 63, wave = tid >> 6;
  const int wr = wave >> 1, wc = wave & 1, cl = lane & 15, cq = lane >> 4;
  f32x4 acc[4][4];
  #pragma unroll
  for (int i=0;i<4;i++)
    #pragma unroll
    for (int j=0;j<4;j++) acc[i][j] = (f32x4){0.f,0.f,0.f,0.f};
  const int r0 = tid >> 2, kc0 = (tid & 3)*8;
  for (int kt = 0; kt < 512; kt += 32){
    gld_lds16(hb  + (size_t)(r0)*512      + kt + kc0, Ash + (wave*64)*8);
    gld_lds16(hb  + (size_t)(64 + r0)*512 + kt + kc0, Ash + (256 + wave*64)*8);
    gld_lds16(hlb + (size_t)(r0)*512      + kt + kc0, Asl + (wave*64)*8);
    gld_lds16(hlb + (size_t)(64 + r0)*512 + kt + kc0, Asl + (256 + wave*64)*8);
    gld_lds16(Wh  + (size_t)(n0 + r0)*512      + kt + kc0, Bsh + (wave*64)*8);
    gld_lds16(Wh  + (size_t)(n0 + 64 + r0)*512 + kt + kc0, Bsh + (256 + wave*64)*8);
    gld_lds16(Wl  + (size_t)(n0 + r0)*512      + kt + kc0, Bsl + (wave*64)*8);
    gld_lds16(Wl  + (size_t)(n0 + 64 + r0)*512 + kt + kc0, Bsl + (256 + wave*64)*8);
    __syncthreads();
    frag8 ah[4], al[4], bh[4], bl[4];
    #pragma unroll
    for (int i=0;i<4;i++){
      ah[i] = *(const frag8*)(Ash + (64*wr + 16*i + cl)*32 + cq*8);
      al[i] = *(const frag8*)(Asl + (64*wr + 16*i + cl)*32 + cq*8);
      bh[i] = *(const frag8*)(Bsh + (64*wc + 16*i + cl)*32 + cq*8);
      bl[i] = *(const frag8*)(Bsl + (64*wc + 16*i + cl)*32 + cq*8);
    }
    #pragma unroll
    for (int i=0;i<4;i++)
      #pragma unroll
      for (int j=0;j<4;j++){
        acc[i][j] = mfma16(ah[i], bh[j], acc[i][j]);
        acc[i][j] = mfma16(ah[i], bl[j], acc[i][j]);
        acc[i][j] = mfma16(al[i], bh[j], acc[i][j]);
      }
    __syncthreads();
  }
  #pragma unroll
  for (int j=0;j<4;j++){
    int col = n0 + 64*wc + 16*j + cl;
    #pragma unroll
    for (int i=0;i<4;i++){
      int rowb = 64*wr + 16*i + cq*4;
      #pragma unroll
      for (int v=0;v<4;v++){
        int row = rowb + v;
        float val = acc[i][j][v] + Xall[(size_t)(t*128 + row)*1536 + col];
        if (col < 512){
          uf[(size_t)row*512 + col] = sigmoidf_(val);
        } else {
          int c2 = col - 512;
          size_t o = (size_t)row*512 + c2;
          float rh = sigmoidf_(val) * hf[o];
          bf16 h = f2bf(rh);
          rhb[o] = h;
          rhlb[o] = f2bf(rh - bf2f(h));
        }
      }
    }
  }
}

// Phase B: pre = (r*h)@Wc + Xall[:, 1024:1536]; h = u*h + (1-u)*tanh(pre)
__global__ __launch_bounds__(256) void gru_phase_b(
    const bf16* __restrict__ rhb, const bf16* __restrict__ rhlb,
    const bf16* __restrict__ Wch, const bf16* __restrict__ Wcl,
    const float* __restrict__ Xall, float* __restrict__ hf, const float* __restrict__ uf,
    bf16* __restrict__ hb, bf16* __restrict__ hlb,
    bf16* __restrict__ Hh, bf16* __restrict__ Hl, int t)
{
  __shared__ bf16 Ash[128*32], Asl[128*32], Bsh[128*32], Bsl[128*32];
  const int n0 = blockIdx.x*128;
  const int tid = threadIdx.x, lane = tid & 63, wave = tid >> 6;
  const int wr = wave >> 1, wc = wave & 1, cl = lane & 15, cq = lane >> 4;
  f32x4 acc[4][4];
  #pragma unroll
  for (int i=0;i<4;i++)
    #pragma unroll
    for (int j=0;j<4;j++) acc[i][j] = (f32x4){0.f,0.f,0.f,0.f};
  const int r0 = tid >> 2, kc0 = (tid & 3)*8;
  for (int kt = 0; kt < 512; kt += 32){
    gld_lds16(rhb  + (size_t)(r0)*512      + kt + kc0, Ash + (wave*64)*8);
    gld_lds16(rhb  + (size_t)(64 + r0)*512 + kt + kc0, Ash + (256 + wave*64)*8);
    gld_lds16(rhlb + (size_t)(r0)*512      + kt + kc0, Asl + (wave*64)*8);
    gld_lds16(rhlb + (size_t)(64 + r0)*512 + kt + kc0, Asl + (256 + wave*64)*8);
    gld_lds16(Wch  + (size_t)(n0 + r0)*512      + kt + kc0, Bsh + (wave*64)*8);
    gld_lds16(Wch  + (size_t)(n0 + 64 + r0)*512 + kt + kc0, Bsh + (256 + wave*64)*8);
    gld_lds16(Wcl  + (size_t)(n0 + r0)*512      + kt + kc0, Bsl + (wave*64)*8);
    gld_lds16(Wcl  + (size_t)(n0 + 64 + r0)*512 + kt + kc0, Bsl + (256 + wave*64)*8);
    __syncthreads();
    frag8 ah[4], al[4], bh[4], bl[4];
    #pragma unroll
    for (int i=0;i<4;i++){
      ah[i] = *(const frag8*)(Ash + (64*wr + 16*i + cl)*32 + cq*8);
      al[i] = *(const frag8*)(Asl + (64*wr + 16*i + cl)*32 + cq*8);
      bh[i] = *(const frag8*)(Bsh + (64*wc + 16*i + cl)*32 + cq*8);
      bl[i] = *(const frag8*)(Bsl + (64*wc + 16*i + cl)*32 + cq*8);
    }
    #pragma unroll
    for (int i=0;i<4;i++)
      #pragma unroll
      for (int j=0;j<4;j++){
        acc[i][j] = mfma16(ah[i], bh[j], acc[i][j]);
        acc[i][j] = mfma16(ah[i], bl[j], acc[i][j]);
        acc[i][j] = mfma16(al[i], bh[j], acc[i][j]);
      }
    __syncthreads();
  }
  #pragma unroll
  for (int j=0;j<4;j++){
    int col = n0 + 64*wc + 16*j + cl;
    #pragma unroll
    for (int i=0;i<4;i++){
      int rowb = 64*wr + 16*i + cq*4;
      #pragma unroll
      for (int v=0;v<4;v++){
        int row = rowb + v;
        float val = acc[i][j][v] + Xall[(size_t)(t*128 + row)*1536 + 1024 + col];
        float hh = tanhf_(val);
        size_t o = (size_t)row*512 + col;
        float u = uf[o], hold = hf[o];
        float hn = u*hold + (1.f - u)*hh;
        hf[o] = hn;
        bf16 hhi = f2bf(hn);
        bf16 hlo = f2bf(hn - bf2f(hhi));
        hb[o] = hhi; hlb[o] = hlo;
        size_t ot = (size_t)(t*128 + row)*512 + col;
        Hh[ot] = hhi; Hl[ot] = hlo;
      }
    }
  }
}

// ---------------- hidden output (f32) ----------------
__global__ __launch_bounds__(256) void hidden_out(const float* __restrict__ h0f,
    const float* __restrict__ h1f, float* __restrict__ out){
  int i = blockIdx.x*256 + threadIdx.x;   // 0..131071
  out[i] = (i < 65536) ? h0f[i] : h1f[i - 65536];
}

// ---------------- host ----------------
extern "C" void kernel_launch(void* const* d_in, const int* in_sizes, int n_in,
                              void* d_out, int out_size, void* d_ws, size_t ws_size,
                              hipStream_t stream)
{
  const void* tokens = d_in[0];
  const void* cnn  = d_in[1];
  const void* emb  = d_in[2];
  const void* Win  = d_in[3];
  const void* bin  = d_in[4];
  const void* Wout = d_in[5];
  const void* bout = d_in[6];
  const void* Wu0  = d_in[7];
  const void* bu0  = d_in[8];
  const void* Wr0  = d_in[9];
  const void* br0  = d_in[10];
  const void* Wc0  = d_in[11];
  const void* bc0  = d_in[12];
  const void* Wu1  = d_in[13];
  const void* bu1  = d_in[14];
  const void* Wr1  = d_in[15];
  const void* br1  = d_in[16];
  const void* Wc1  = d_in[17];
  const void* bc1  = d_in[18];

  char* wp = (char*)d_ws;
  auto alloc = [&](size_t bytes) -> char* {
    char* r = wp; wp += (bytes + 255) & ~(size_t)255; return r;
  };
  auto B2 = [](size_t n){ return n*2; };
  bf16* WinTh  = (bf16*)alloc(B2(512*2048)); bf16* WinTl  = (bf16*)alloc(B2(512*2048));
  bf16* WoutTh = (bf16*)alloc(B2((size_t)10112*512));
  // stacked gate weights: rows [0,512)=u, [512,1024)=r, [1024,1536)=c
  bf16* W0xTh = (bf16*)alloc(B2((size_t)1536*1024)); bf16* W0xTl = (bf16*)alloc(B2((size_t)1536*1024));
  bf16* W0hTh = (bf16*)alloc(B2((size_t)1536*512));  bf16* W0hTl = (bf16*)alloc(B2((size_t)1536*512));
  bf16* W1xTh = (bf16*)alloc(B2((size_t)1536*512));  bf16* W1xTl = (bf16*)alloc(B2((size_t)1536*512));
  bf16* W1hTh = (bf16*)alloc(B2((size_t)1536*512));  bf16* W1hTl = (bf16*)alloc(B2((size_t)1536*512));
  bf16* embH = (bf16*)alloc(B2((size_t)10000*512));
  bf16* embL = (bf16*)alloc(B2((size_t)10000*512));
  bf16* cnnH = (bf16*)alloc(B2(128*2048)); bf16* cnnL = (bf16*)alloc(B2(128*2048));
  bf16* pH   = (bf16*)alloc(B2(128*512)); bf16* pL = (bf16*)alloc(B2(128*512));
  bf16* X0AH = (bf16*)alloc(B2((size_t)3200*1024)); bf16* X0AL = (bf16*)alloc(B2((size_t)3200*1024));
  float* Xall = (float*)alloc((size_t)3200*1536*4);   // shared by layer 0 and layer 1
  bf16* H0h = (bf16*)alloc(B2((size_t)3200*512)); bf16* H0l = (bf16*)alloc(B2((size_t)3200*512));
  bf16* H1h = (bf16*)alloc(B2((size_t)3200*512)); bf16* H1l = (bf16*)alloc(B2((size_t)3200*512));
  float* binF = (float*)alloc(512*4);
  float* boutF = (float*)alloc(10000*4);
  float* b0all = (float*)alloc(1536*4);
  float* b1all = (float*)alloc(1536*4);
  float* h0f = (float*)alloc(65536*4); float* h1f = (float*)alloc(65536*4);
  float* uf0 = (float*)alloc(65536*4); float* uf1 = (float*)alloc(65536*4);
  bf16* h0b = (bf16*)alloc(B2(65536)); bf16* h0lb = (bf16*)alloc(B2(65536));
  bf16* h1b = (bf16*)alloc(B2(65536)); bf16* h1lb = (bf16*)alloc(B2(65536));
  bf16* rh0 = (bf16*)alloc(B2(65536)); bf16* rh0l = (bf16*)alloc(B2(65536));
  bf16* rh1 = (bf16*)alloc(B2(65536)); bf16* rh1l = (bf16*)alloc(B2(65536));
  int* flags = (int*)alloc(256);

  detect_kernel<<<1, 256, 0, stream>>>((const unsigned short*)emb, (const int*)tokens, flags);
  cvt_split<<<5000, 256, 0, stream>>>(emb, embH, embL, 5120000, flags);
  cvt_split<<<256, 256, 0, stream>>>(cnn, cnnH, cnnL, 262144, flags);
  CDs cds;
  cds.d[0] = {bin,  binF,  512};
  cds.d[1] = {bout, boutF, 10000};
  cds.d[2] = {bu0,  b0all + 0,    512};
  cds.d[3] = {br0,  b0all + 512,  512};
  cds.d[4] = {bc0,  b0all + 1024, 512};
  cds.d[5] = {bu1,  b1all + 0,    512};
  cds.d[6] = {br1,  b1all + 512,  512};
  cds.d[7] = {bc1,  b1all + 1024, 512};
  cvt_f32_batch<<<dim3(40, 8), 256, 0, stream>>>(cds, flags);

  TDs tds;
  tds.d[0]  = {Win,  WinTh, WinTl, 0, 2048, 512, 512, 512};
  tds.d[1]  = {Wout, WoutTh, nullptr, 0, 512, 10112, 10000, 10000};
  // layer 0: Wu0/Wr0 rows [0,1024)=x, [1024,1536)=h ; Wc0 rows [0,512)=rh, [512,1536)=x
  tds.d[2]  = {Wu0, W0xTh,               W0xTl,               0,    1024, 512, 512, 512};
  tds.d[3]  = {Wr0, W0xTh + 512*1024,    W0xTl + 512*1024,    0,    1024, 512, 512, 512};
  tds.d[4]  = {Wc0, W0xTh + 1024*1024,   W0xTl + 1024*1024,   512,  1024, 512, 512, 512};
  tds.d[5]  = {Wu0, W0hTh,               W0hTl,               1024, 512,  512, 512, 512};
  tds.d[6]  = {Wr0, W0hTh + 512*512,     W0hTl + 512*512,     1024, 512,  512, 512, 512};
  tds.d[7]  = {Wc0, W0hTh + 1024*512,    W0hTl + 1024*512,    0,    512,  512, 512, 512};
  // layer 1: Wu1/Wr1 rows [0,512)=x, [512,1024)=h ; Wc1 rows [0,512)=rh, [512,1024)=x
  tds.d[8]  = {Wu1, W1xTh,               W1xTl,               0,    512,  512, 512, 512};
  tds.d[9]  = {Wr1, W1xTh + 512*512,     W1xTl + 512*512,     0,    512,  512, 512, 512};
  tds.d[10] = {Wc1, W1xTh + 1024*512,    W1xTl + 1024*512,    512,  512,  512, 512, 512};
  tds.d[11] = {Wu1, W1hTh,               W1hTl,               512,  512,  512, 512, 512};
  tds.d[12] = {Wr1, W1hTh + 512*512,     W1hTl + 512*512,     512,  512,  512, 512, 512};
  tds.d[13] = {Wc1, W1hTh + 1024*512,    W1hTl + 1024*512,    0,    512,  512, 512, 512};
  transpose_many<<<dim3(5056, 14), 256, 0, stream>>>(tds, flags);

  init_zero<<<256, 256, 0, stream>>>(h0f, h1f, h0b, h0lb, h1b, h1lb);

  // p = leaky(cnn@Win + bin), split bf16 out
  gemm_split<1><<<dim3(4, 1), 256, 0, stream>>>(
      cnnH, cnnL, WinTh, WinTl, binF, nullptr, pH, pL, 2048, 512);
  build_x0a<<<3200, 256, 0, stream>>>((const int*)tokens, embH, embL, pH, pL, X0AH, X0AL, flags);
  // layer-0 gate pre-acts: Xall[3200,1536] = X0A @ W0xT + b0all
  gemm_split<0><<<dim3(12, 25), 256, 0, stream>>>(
      X0AH, X0AL, W0xTh, W0xTl, b0all, Xall, nullptr, nullptr, 1024, 1536);
  for (int t = 0; t < T_N; t++){
    gru_phase_a<<<8, 256, 0, stream>>>(h0b, h0lb, W0hTh, W0hTl, Xall, h0f, uf0, rh0, rh0l, t);
    gru_phase_b<<<4, 256, 0, stream>>>(rh0, rh0l, W0hTh + (size_t)1024*512, W0hTl + (size_t)1024*512,
                                       Xall, h0f, uf0, h0b, h0lb, H0h, H0l, t);
  }
  // layer-1 gate pre-acts (reuses Xall)
  gemm_split<0><<<dim3(12, 25), 256, 0, stream>>>(
      H0h, H0l, W1xTh, W1xTl, b1all, Xall, nullptr, nullptr, 512, 1536);
  for (int t = 0; t < T_N; t++){
    gru_phase_a<<<8, 256, 0, stream>>>(h1b, h1lb, W1hTh, W1hTl, Xall, h1f, uf1, rh1, rh1l, t);
    gru_phase_b<<<4, 256, 0, stream>>>(rh1, rh1l, W1hTh + (size_t)1024*512, W1hTl + (size_t)1024*512,
                                       Xall, h1f, uf1, h1b, h1lb, H1h, H1l, t);
  }
  float* out = (float*)d_out;
  gemm_logits<<<dim3(79, 25), 256, 0, stream>>>(H1h, WoutTh, boutF, out, 512, 10000);
  hidden_out<<<512, 256, 0, stream>>>(h0f, h1f, out + 32000000);
}